// Round 12
// baseline (432.803 us; speedup 1.0000x reference)
//
#include <hip/hip_runtime.h>
#include <hip/hip_bf16.h>

// Problem constants (match reference setup_inputs()).
#define NN   100000   // nodes
#define NE   600000   // edges
#define FIN  128
#define H0   64
#define H1   128
#define NG   512
#define BM   64       // GEMM row-tile
#define XP   132      // padded xs row stride (FIN+4): breaks 4-row bank alias
#define AP   68       // padded as row stride (H0+4)

// ---------------------------------------------------------------------------
__global__ void hist_kernel(const int* __restrict__ idx, int* __restrict__ cnt, int n)
{
    int i = blockIdx.x * blockDim.x + threadIdx.x;
    int stride = gridDim.x * blockDim.x;
    for (; i < n; i += stride) atomicAdd(&cnt[idx[i]], 1);
}

// batch is SORTED -> per-graph counts via two binary searches, no atomics.
__global__ void batch_count_kernel(const int* __restrict__ batch,
                                   int* __restrict__ cnt, int n)
{
    const int g = blockIdx.x * blockDim.x + threadIdx.x;
    if (g >= NG) return;
    int lo = 0, hi = n;
    while (lo < hi) { const int m = (lo + hi) >> 1; if (batch[m] < g) lo = m + 1; else hi = m; }
    const int start = lo;
    lo = 0; hi = n;
    while (lo < hi) { const int m = (lo + hi) >> 1; if (batch[m] < g + 1) lo = m + 1; else hi = m; }
    cnt[g] = lo - start;
}

__global__ void dinv_kernel(const int* __restrict__ deg, float* __restrict__ dinv, int n)
{
    int i = blockIdx.x * blockDim.x + threadIdx.x;
    if (i < n) dinv[i] = 1.0f / sqrtf((float)(deg[i] + 1));
}

// ---------------------------------------------------------------------------
// CSR build: exclusive scan of deg -> rowptr, then counting-sort src by dst.
__global__ __launch_bounds__(256) void scan1_kernel(
    const int* __restrict__ deg, int* __restrict__ rp, int* __restrict__ bsum, int n)
{
    __shared__ int tmp[256];
    const int t = threadIdx.x;
    const int i = blockIdx.x * 256 + t;
    int v = (i < n) ? deg[i] : 0;
    tmp[t] = v;
    __syncthreads();
    #pragma unroll
    for (int off = 1; off < 256; off <<= 1) {
        int a = (t >= off) ? tmp[t - off] : 0;
        __syncthreads();
        tmp[t] += a;
        __syncthreads();
    }
    if (i < n) rp[i] = tmp[t] - v;
    if (t == 255) bsum[blockIdx.x] = tmp[255];
}

__global__ __launch_bounds__(512) void scan2_kernel(
    const int* __restrict__ bsum, int* __restrict__ boff, int nb)
{
    __shared__ int tmp[512];
    const int t = threadIdx.x;
    int v = (t < nb) ? bsum[t] : 0;
    tmp[t] = v;
    __syncthreads();
    #pragma unroll
    for (int off = 1; off < 512; off <<= 1) {
        int a = (t >= off) ? tmp[t - off] : 0;
        __syncthreads();
        tmp[t] += a;
        __syncthreads();
    }
    if (t < nb) boff[t] = tmp[t] - v;
}

__global__ __launch_bounds__(256) void scan3_kernel(
    int* __restrict__ rp, int* __restrict__ wcur, const int* __restrict__ boff, int n)
{
    const int i = blockIdx.x * 256 + threadIdx.x;
    if (i < n) {
        const int v = rp[i] + boff[blockIdx.x];
        rp[i] = v;
        wcur[i] = v;
    }
}

__global__ void fill_kernel(const int* __restrict__ src, const int* __restrict__ dst,
                            int* __restrict__ wcur, int* __restrict__ csr, int ne)
{
    int i = blockIdx.x * blockDim.x + threadIdx.x;
    const int stride = gridDim.x * blockDim.x;
    for (; i < ne; i += stride) {
        const int d = dst[i];
        const int p = atomicAdd(&wcur[d], 1);
        csr[p] = src[i];
    }
}

// ---------------------------------------------------------------------------
// GEMM1: h0s[row] = (x[row] @ Wc0) * dinv[row]   [100k,128]@[128,64]
// Register-tiled 4x4. W read DIRECTLY from global (32 KB, L1/L2-resident;
// each 16-lane group = one 256B broadcast request) -> LDS holds only the
// padded x tile (33 KB): halves LDS-read traffic, 4 blocks/CU (was 2).
__global__ __launch_bounds__(256, 4) void gemm1_kernel(
    const float* __restrict__ x, const float* __restrict__ W,
    const float* __restrict__ dinv, float* __restrict__ h0s, int n)
{
    __shared__ float xs[BM * XP];    // 33 KB [r][k] padded
    const int t = threadIdx.x;
    const int lane = t & 63;
    const int w    = t >> 6;              // 0..3
    const int rsub = lane >> 4;           // 0..3
    const int j0   = (lane & 15) * 4;     // col base (16 lanes -> 256B contig)
    const int wrow = w * 16 + rsub * 4;   // row base within tile
    const int ntiles = (n + BM - 1) / BM;

    for (int tile = blockIdx.x; tile < ntiles; tile += gridDim.x) {
        const int row0  = tile * BM;
        const int nrows = min(BM, n - row0);
        __syncthreads();                  // xs reuse fence
        {
            const float4* xg = (const float4*)(x + (size_t)row0 * FIN);
            const int nf4 = nrows * (FIN / 4);        // 2048 full tile
            for (int idx = t; idx < nf4; idx += 256) {
                const int r  = idx >> 5;              // FIN/4 = 32 f4/row
                const int c4 = idx & 31;
                *(float4*)&xs[r * XP + (c4 << 2)] = xg[idx];
            }
        }
        __syncthreads();

        float acc[4][4] = {};
        const float* xr = xs + wrow * XP;
        #pragma unroll 4
        for (int k = 0; k < FIN; k += 4) {
            const float4 w0 = *(const float4*)&W[(k + 0) * H0 + j0];
            const float4 w1 = *(const float4*)&W[(k + 1) * H0 + j0];
            const float4 w2 = *(const float4*)&W[(k + 2) * H0 + j0];
            const float4 w3 = *(const float4*)&W[(k + 3) * H0 + j0];
            #pragma unroll
            for (int r = 0; r < 4; ++r) {
                const float4 xv = *(const float4*)&xr[r * XP + k]; // 16-lane bcast
                acc[r][0] += xv.x * w0.x; acc[r][0] += xv.y * w1.x;
                acc[r][0] += xv.z * w2.x; acc[r][0] += xv.w * w3.x;
                acc[r][1] += xv.x * w0.y; acc[r][1] += xv.y * w1.y;
                acc[r][1] += xv.z * w2.y; acc[r][1] += xv.w * w3.y;
                acc[r][2] += xv.x * w0.z; acc[r][2] += xv.y * w1.z;
                acc[r][2] += xv.z * w2.z; acc[r][2] += xv.w * w3.z;
                acc[r][3] += xv.x * w0.w; acc[r][3] += xv.y * w1.w;
                acc[r][3] += xv.z * w2.w; acc[r][3] += xv.w * w3.w;
            }
        }
        #pragma unroll
        for (int r = 0; r < 4; ++r) {
            const int row = row0 + wrow + r;
            if (row < n) {
                const float dv = dinv[row];
                float4 o;
                o.x = acc[r][0] * dv; o.y = acc[r][1] * dv;
                o.z = acc[r][2] * dv; o.w = acc[r][3] * dv;
                *(float4*)&h0s[(size_t)row * H0 + j0] = o;
            }
        }
    }
}

// ---------------------------------------------------------------------------
// CSR gather (one wave per node, lane = feature). Rows pre-scaled by dinv[s]:
//   t = sum_{s in N(d)} hin[s] + hin[d]
// Neighbor indices loaded ONCE per node as a lane-parallel coalesced vector,
// broadcast via __shfl; h-loads 4-deep for latency hiding.
// MODE 0: hout = relu(t*dinv[d] + bias) * dinv[d]   MODE 1: hout = t*dinv[d]
template <int MODE>
__global__ __launch_bounds__(256) void gather_kernel(
    const float* __restrict__ hin, const int* __restrict__ rowptr,
    const int* __restrict__ deg, const int* __restrict__ csr,
    const float* __restrict__ dinv, const float* __restrict__ bias,
    float* __restrict__ hout, int n)
{
    const int lane = threadIdx.x & 63;
    int wid = (blockIdx.x * blockDim.x + threadIdx.x) >> 6;
    const int nw = (gridDim.x * blockDim.x) >> 6;
    for (int d = wid; d < n; d += nw) {
        const int r0  = rowptr[d];
        const int cnt = deg[d];
        float acc = hin[(size_t)d * H0 + lane];            // self loop
        for (int base = 0; base < cnt; base += 64) {
            const int m = min(64, cnt - base);
            const int sv = (lane < m) ? csr[r0 + base + lane] : 0; // 1 coalesced load
            int k = 0;
            for (; k + 3 < m; k += 4) {
                const int s0 = __shfl(sv, k);
                const int s1 = __shfl(sv, k + 1);
                const int s2 = __shfl(sv, k + 2);
                const int s3 = __shfl(sv, k + 3);
                const float v0 = hin[(size_t)s0 * H0 + lane];
                const float v1 = hin[(size_t)s1 * H0 + lane];
                const float v2 = hin[(size_t)s2 * H0 + lane];
                const float v3 = hin[(size_t)s3 * H0 + lane];
                acc += v0; acc += v1; acc += v2; acc += v3;
            }
            for (; k < m; ++k) {
                const int s = __shfl(sv, k);
                acc += hin[(size_t)s * H0 + lane];
            }
        }
        const float dv = dinv[d];
        if (MODE == 0)
            hout[(size_t)d * H0 + lane] = fmaxf(acc * dv + bias[lane], 0.f) * dv;
        else
            hout[(size_t)d * H0 + lane] = acc * dv;
    }
}

// ---------------------------------------------------------------------------
// GEMM2 [100k,64]@[64,128] + bias + relu + mean-pool. Register-tiled 4x8.
// W read directly from global (L1/L2-resident); LDS = padded a tile + pool
// buffers (~20 KB) -> much higher occupancy.
__global__ __launch_bounds__(256, 4) void gemm2_pool_kernel(
    const float* __restrict__ a /*agg1*/, const float* __restrict__ W /*64x128*/,
    const float* __restrict__ bc1, const int* __restrict__ batch,
    float* __restrict__ gsum, int n)
{
    __shared__ float as[BM * AP];    // 17 KB [r][k] padded
    __shared__ float red[4][H1];     // 2 KB per-wave col partials
    __shared__ int   bs[BM];
    const int t = threadIdx.x;
    const int lane = t & 63;
    const int w    = t >> 6;              // 0..3
    const int rsub = lane >> 4;           // 0..3
    const int cA   = (lane & 15) * 4;     // cols cA..cA+3
    const int cB   = cA + 64;             // cols cB..cB+3
    const int wrow = w * 16 + rsub * 4;   // row base within tile
    const float4 bA = *(const float4*)&bc1[cA];
    const float4 bB = *(const float4*)&bc1[cB];
    const int ntiles = (n + BM - 1) / BM;

    for (int tile = blockIdx.x; tile < ntiles; tile += gridDim.x) {
        const int row0  = tile * BM;
        const int nrows = min(BM, n - row0);
        __syncthreads();                  // as/red/bs reuse fence
        {
            const float4* ag = (const float4*)(a + (size_t)row0 * H0);
            const int nf4 = nrows * (H0 / 4);         // 1024 full tile
            for (int idx = t; idx < nf4; idx += 256) {
                const int r  = idx >> 4;              // H0/4 = 16 f4/row
                const int c4 = idx & 15;
                *(float4*)&as[r * AP + (c4 << 2)] = ag[idx];
            }
            if (t < nrows) bs[t] = batch[row0 + t];
        }
        __syncthreads();

        float acc[4][8] = {};
        const float* ar = as + wrow * AP;
        #pragma unroll 4
        for (int k = 0; k < H0; k += 4) {
            float4 wa[4], wb[4];
            #pragma unroll
            for (int kk = 0; kk < 4; ++kk) {
                wa[kk] = *(const float4*)&W[(k + kk) * H1 + cA];
                wb[kk] = *(const float4*)&W[(k + kk) * H1 + cB];
            }
            #pragma unroll
            for (int r = 0; r < 4; ++r) {
                const float4 xv = *(const float4*)&ar[r * AP + k]; // 16-lane bcast
                acc[r][0] += xv.x * wa[0].x; acc[r][0] += xv.y * wa[1].x;
                acc[r][0] += xv.z * wa[2].x; acc[r][0] += xv.w * wa[3].x;
                acc[r][1] += xv.x * wa[0].y; acc[r][1] += xv.y * wa[1].y;
                acc[r][1] += xv.z * wa[2].y; acc[r][1] += xv.w * wa[3].y;
                acc[r][2] += xv.x * wa[0].z; acc[r][2] += xv.y * wa[1].z;
                acc[r][2] += xv.z * wa[2].z; acc[r][2] += xv.w * wa[3].z;
                acc[r][3] += xv.x * wa[0].w; acc[r][3] += xv.y * wa[1].w;
                acc[r][3] += xv.z * wa[2].w; acc[r][3] += xv.w * wa[3].w;
                acc[r][4] += xv.x * wb[0].x; acc[r][4] += xv.y * wb[1].x;
                acc[r][4] += xv.z * wb[2].x; acc[r][4] += xv.w * wb[3].x;
                acc[r][5] += xv.x * wb[0].y; acc[r][5] += xv.y * wb[1].y;
                acc[r][5] += xv.z * wb[2].y; acc[r][5] += xv.w * wb[3].y;
                acc[r][6] += xv.x * wb[0].z; acc[r][6] += xv.y * wb[1].z;
                acc[r][6] += xv.z * wb[2].z; acc[r][6] += xv.w * wb[3].z;
                acc[r][7] += xv.x * wb[0].w; acc[r][7] += xv.y * wb[1].w;
                acc[r][7] += xv.z * wb[2].w; acc[r][7] += xv.w * wb[3].w;
            }
        }

        // bias+relu into per-row values, then pool (batch sorted).
        const float bv[8] = {bA.x, bA.y, bA.z, bA.w, bB.x, bB.y, bB.z, bB.w};
        const bool uni = (nrows == BM) && (bs[0] == bs[BM - 1]); // block-uniform
        if (uni) {
            float s[8];
            #pragma unroll
            for (int c = 0; c < 8; ++c) {
                s[c] = fmaxf(acc[0][c] + bv[c], 0.f) + fmaxf(acc[1][c] + bv[c], 0.f)
                     + fmaxf(acc[2][c] + bv[c], 0.f) + fmaxf(acc[3][c] + bv[c], 0.f);
                s[c] += __shfl_xor(s[c], 16);      // merge rsub pairs
                s[c] += __shfl_xor(s[c], 32);      // all 4 rsubs -> 16-row sum
            }
            if (rsub == 0) {
                #pragma unroll
                for (int c = 0; c < 4; ++c) red[w][cA + c] = s[c];
                #pragma unroll
                for (int c = 0; c < 4; ++c) red[w][cB + c] = s[c + 4];
            }
            __syncthreads();
            if (t < H1)
                atomicAdd(&gsum[(size_t)bs[0] * H1 + t],
                          red[0][t] + red[1][t] + red[2][t] + red[3][t]);
        } else {
            int gcur = -1; float run[8];
            #pragma unroll
            for (int r = 0; r < 4; ++r) {
                const int row = wrow + r;
                if (row < nrows) {
                    const int g = bs[row];
                    if (g != gcur) {
                        if (gcur >= 0) {
                            #pragma unroll
                            for (int c = 0; c < 4; ++c)
                                atomicAdd(&gsum[(size_t)gcur * H1 + cA + c], run[c]);
                            #pragma unroll
                            for (int c = 0; c < 4; ++c)
                                atomicAdd(&gsum[(size_t)gcur * H1 + cB + c], run[c + 4]);
                        }
                        gcur = g;
                        #pragma unroll
                        for (int c = 0; c < 8; ++c) run[c] = fmaxf(acc[r][c] + bv[c], 0.f);
                    } else {
                        #pragma unroll
                        for (int c = 0; c < 8; ++c) run[c] += fmaxf(acc[r][c] + bv[c], 0.f);
                    }
                }
            }
            if (gcur >= 0) {
                #pragma unroll
                for (int c = 0; c < 4; ++c)
                    atomicAdd(&gsum[(size_t)gcur * H1 + cA + c], run[c]);
                #pragma unroll
                for (int c = 0; c < 4; ++c)
                    atomicAdd(&gsum[(size_t)gcur * H1 + cB + c], run[c + 4]);
            }
        }
    }
}

// ---------------------------------------------------------------------------
// Per-graph MLP head: mean -> Linear(128,512) -> relu-Linear chain -> scalar
__global__ __launch_bounds__(256) void mlp_kernel(
    const float* __restrict__ gsum, const int* __restrict__ cnt,
    const float* __restrict__ Wf,  const float* __restrict__ bf,
    const float* __restrict__ Wh0, const float* __restrict__ bh0,
    const float* __restrict__ Wh1, const float* __restrict__ bh1,
    const float* __restrict__ Wh2, const float* __restrict__ bh2,
    const float* __restrict__ Wo,  const float* __restrict__ bo,
    float* __restrict__ out)
{
    __shared__ float gm[128];
    __shared__ float e0[512];
    __shared__ float e1[256];
    __shared__ float e2[128];
    __shared__ float e3[64];
    const int gi = blockIdx.x;
    const int t  = threadIdx.x;

    if (t < 128) {
        const int c = cnt[gi];
        gm[t] = gsum[gi * 128 + t] * (1.0f / (float)max(c, 1));
    }
    __syncthreads();

    for (int jj = t; jj < 512; jj += 256) {
        float acc = bf[jj];
        for (int k = 0; k < 128; ++k) acc += gm[k] * Wf[k * 512 + jj];
        e0[jj] = acc;
    }
    __syncthreads();

    {
        float acc = bh0[t];
        for (int k = 0; k < 512; ++k) acc += e0[k] * Wh0[k * 256 + t];
        if (t < 256) e1[t] = fmaxf(acc, 0.f);
    }
    __syncthreads();

    if (t < 128) {
        float acc = bh1[t];
        for (int k = 0; k < 256; ++k) acc += e1[k] * Wh1[k * 128 + t];
        e2[t] = fmaxf(acc, 0.f);
    }
    __syncthreads();

    if (t < 64) {
        float acc = bh2[t];
        for (int k = 0; k < 128; ++k) acc += e2[k] * Wh2[k * 64 + t];
        e3[t] = fmaxf(acc, 0.f);
    }
    __syncthreads();

    if (t < 64) {
        float p = e3[t] * Wo[t];
        #pragma unroll
        for (int off = 32; off > 0; off >>= 1) p += __shfl_down(p, off);
        if (t == 0) out[gi] = p + bo[0];
    }
}

// ---------------------------------------------------------------------------
extern "C" void kernel_launch(void* const* d_in, const int* in_sizes, int n_in,
                              void* d_out, int out_size, void* d_ws, size_t ws_size,
                              hipStream_t stream)
{
    const float* x    = (const float*)d_in[0];
    const int*   src  = (const int*)  d_in[1];
    const int*   dst  = (const int*)  d_in[2];
    const int*   batch= (const int*)  d_in[3];
    const float* Wc0  = (const float*)d_in[4];
    const float* bc0  = (const float*)d_in[5];
    const float* Wc1  = (const float*)d_in[6];
    const float* bc1  = (const float*)d_in[7];
    const float* Wf   = (const float*)d_in[8];
    const float* bf   = (const float*)d_in[9];
    const float* Wh0  = (const float*)d_in[10];
    const float* bh0  = (const float*)d_in[11];
    const float* Wh1  = (const float*)d_in[12];
    const float* bh1  = (const float*)d_in[13];
    const float* Wh2  = (const float*)d_in[14];
    const float* bh2  = (const float*)d_in[15];
    const float* Wo   = (const float*)d_in[16];
    const float* bo   = (const float*)d_in[17];
    float* out = (float*)d_out;

    const int n = NN, ne = NE;
    const int nblk = (n + 255) / 256;   // 391 scan blocks
    const int ntiles = (n + BM - 1) / BM;  // 1563

    char* ws = (char*)d_ws;
    size_t off = 0;
    auto alloc = [&](size_t bytes) {
        void* p = ws + off;
        off = (off + bytes + 255) & ~(size_t)255;
        return p;
    };
    int*   deg    = (int*)  alloc((size_t)n * 4);
    float* dinv   = (float*)alloc((size_t)n * 4);
    int*   rowptr = (int*)  alloc((size_t)n * 4);
    int*   wcur   = (int*)  alloc((size_t)n * 4);
    int*   bsum   = (int*)  alloc(512 * 4);
    int*   boff   = (int*)  alloc(512 * 4);
    int*   csr    = (int*)  alloc((size_t)ne * 4);
    float* h0s    = (float*)alloc((size_t)n * H0 * 4);
    float* h1s    = (float*)alloc((size_t)n * H0 * 4);
    float* agg1   = (float*)alloc((size_t)n * H0 * 4);
    float* gsum   = (float*)alloc((size_t)NG * H1 * 4);
    int*   cnt    = (int*)  alloc((size_t)NG * 4);

    hipMemsetAsync(deg,  0, (size_t)n * 4, stream);
    hipMemsetAsync(gsum, 0, (size_t)NG * H1 * 4, stream);

    // Degrees (random-address atomics) + batch counts (binary search).
    hist_kernel<<<1024, 256, 0, stream>>>(dst, deg, ne);
    batch_count_kernel<<<2, 256, 0, stream>>>(batch, cnt, n);
    dinv_kernel<<<nblk, 256, 0, stream>>>(deg, dinv, n);

    // CSR build (once, reused by both layers).
    scan1_kernel<<<nblk, 256, 0, stream>>>(deg, rowptr, bsum, n);
    scan2_kernel<<<1, 512, 0, stream>>>(bsum, boff, nblk);
    scan3_kernel<<<nblk, 256, 0, stream>>>(rowptr, wcur, boff, n);
    fill_kernel<<<1024, 256, 0, stream>>>(src, dst, wcur, csr, ne);

    // Layer 1: GEMM (128->64, pre-scaled by dinv), then CSR-gather aggregate.
    gemm1_kernel<<<ntiles, 256, 0, stream>>>(x, Wc0, dinv, h0s, n);
    gather_kernel<0><<<4096, 256, 0, stream>>>(h0s, rowptr, deg, csr, dinv, bc0, h1s, n);

    // Layer 2: aggregate FIRST (A'(hW) == (A'h)W at F=64), then GEMM 64->128
    // fused with bias+relu+mean-pool.
    gather_kernel<1><<<4096, 256, 0, stream>>>(h1s, rowptr, deg, csr, dinv, bc0, agg1, n);
    gemm2_pool_kernel<<<ntiles, 256, 0, stream>>>(agg1, Wc1, bc1, batch, gsum, n);

    // Per-graph MLP head.
    mlp_kernel<<<NG, 256, 0, stream>>>(gsum, cnt, Wf, bf, Wh0, bh0,
                                       Wh1, bh1, Wh2, bh2, Wo, bo, out);
}